// Round 1
// baseline (411.930 us; speedup 1.0000x reference)
//
#include <hip/hip_runtime.h>

#define N_NODES 50000
#define N_EDGES 800000
#define D_IN 128
#define H1 96
#define H2 64
#define GEMM_NODES 32

// ---------------- degree ----------------
__global__ void init_deg_kernel(float* deg) {
    int i = blockIdx.x * blockDim.x + threadIdx.x;
    if (i < N_NODES) deg[i] = 1.0f;   // self-loop contributes 1
}

__global__ void count_deg_kernel(const int* dst, float* deg) {
    int i = blockIdx.x * blockDim.x + threadIdx.x;
    int stride = gridDim.x * blockDim.x;
    for (int e = i; e < N_EDGES; e += stride)
        atomicAdd(&deg[dst[e]], 1.0f);
}

__global__ void dinv_kernel(const float* deg, float* dinv) {
    int i = blockIdx.x * blockDim.x + threadIdx.x;
    if (i < N_NODES) dinv[i] = rsqrtf(deg[i]);
}

// ---------------- hs = (x @ W1) * dinv[n]  ----------------
// block: 256 threads; fg = tid&31 handles features {fg, fg+32, fg+64};
// ng = tid>>5 handles nodes {base+ng*4 .. +3}. 12 accumulators/thread.
__global__ __launch_bounds__(256) void gemm_kernel(const float* __restrict__ x,
                                                   const float* __restrict__ W1,
                                                   const float* __restrict__ dinv,
                                                   float* __restrict__ hs) {
    __shared__ float sW[D_IN * H1];          // 48 KB
    __shared__ float sx[GEMM_NODES * D_IN];  // 16 KB
    int tid = threadIdx.x;

    // load W1 (12288 floats) as float4
    for (int i = tid; i < D_IN * H1 / 4; i += 256)
        ((float4*)sW)[i] = ((const float4*)W1)[i];

    int base = blockIdx.x * GEMM_NODES;
    // load x tile (32 rows x 128) as float4, guarded for tail
    const float4* x4 = (const float4*)x;
    for (int i = tid; i < GEMM_NODES * D_IN / 4; i += 256) {
        int n = base + i / (D_IN / 4);
        if (n < N_NODES) ((float4*)sx)[i] = x4[(size_t)base * (D_IN / 4) + i];
    }
    __syncthreads();

    int fg = tid & 31;
    int ng = tid >> 5;

    float acc[4][3];
#pragma unroll
    for (int i = 0; i < 4; ++i)
#pragma unroll
        for (int j = 0; j < 3; ++j) acc[i][j] = 0.0f;

#pragma unroll 4
    for (int k = 0; k < D_IN; ++k) {
        float w0 = sW[k * H1 + fg];
        float w1 = sW[k * H1 + fg + 32];
        float w2 = sW[k * H1 + fg + 64];
#pragma unroll
        for (int i = 0; i < 4; ++i) {
            float xv = sx[(ng * 4 + i) * D_IN + k];
            acc[i][0] = fmaf(xv, w0, acc[i][0]);
            acc[i][1] = fmaf(xv, w1, acc[i][1]);
            acc[i][2] = fmaf(xv, w2, acc[i][2]);
        }
    }

#pragma unroll
    for (int i = 0; i < 4; ++i) {
        int n = base + ng * 4 + i;
        if (n < N_NODES) {
            float dv = dinv[n];
            hs[(size_t)n * H1 + fg]      = acc[i][0] * dv;
            hs[(size_t)n * H1 + fg + 32] = acc[i][1] * dv;
            hs[(size_t)n * H1 + fg + 64] = acc[i][2] * dv;
        }
    }
}

// ---------------- edge scatter-add: agg[d] += hs[s] ----------------
// 128-thread groups: lane f<96 handles feature f of one edge at a time.
__global__ void aggregate_kernel(const int* __restrict__ src,
                                 const int* __restrict__ dst,
                                 const float* __restrict__ hs,
                                 float* __restrict__ agg) {
    int gid = blockIdx.x * blockDim.x + threadIdx.x;
    int group = gid >> 7;
    int f = gid & 127;
    int ngroups = (gridDim.x * blockDim.x) >> 7;
    for (int e = group; e < N_EDGES; e += ngroups) {
        int s = src[e];
        int d = dst[e];
        if (f < H1)
            atomicAdd(&agg[(size_t)d * H1 + f], hs[(size_t)s * H1 + f]);
    }
}

// ---------------- pooled g[f] = sum_n relu(dinv[n]*(agg+hs) + b1[f]) ----------------
__global__ void pool_kernel(const float* __restrict__ agg,
                            const float* __restrict__ hs,
                            const float* __restrict__ dinv,
                            const float* __restrict__ b1,
                            float* __restrict__ g) {
    int f = threadIdx.x;  // blockDim = 128
    if (f >= H1) return;
    float bf = b1[f];
    float acc = 0.0f;
    for (int n = blockIdx.x; n < N_NODES; n += gridDim.x) {
        float dv = dinv[n];
        float v = dv * (agg[(size_t)n * H1 + f] + hs[(size_t)n * H1 + f]) + bf;
        acc += fmaxf(v, 0.0f);
    }
    atomicAdd(&g[f], acc);
}

// ---------------- tiny MLP head ----------------
__global__ void mlp_kernel(const float* __restrict__ g,
                           const float* __restrict__ lw1, const float* __restrict__ lb1,
                           const float* __restrict__ lw2, const float* __restrict__ lb2,
                           const float* __restrict__ lw3, const float* __restrict__ lb3,
                           float* __restrict__ out) {
    __shared__ float sg[H1], v1[H1], v2[H2];
    int t = threadIdx.x;  // blockDim = 128
    if (t < H1) sg[t] = g[t];
    __syncthreads();
    if (t < H1) {
        float a = lb1[t];
        for (int k = 0; k < H1; ++k) a = fmaf(sg[k], lw1[k * H1 + t], a);
        v1[t] = fmaxf(a, 0.0f);
    }
    __syncthreads();
    if (t < H2) {
        float a = lb2[t];
        for (int k = 0; k < H1; ++k) a = fmaf(v1[k], lw2[k * H2 + t], a);
        v2[t] = fmaxf(a, 0.0f);
    }
    __syncthreads();
    if (t == 0) {
        float a = lb3[0];
        for (int k = 0; k < H2; ++k) a = fmaf(v2[k], lw3[k], a);
        out[0] = a;
    }
}

extern "C" void kernel_launch(void* const* d_in, const int* in_sizes, int n_in,
                              void* d_out, int out_size, void* d_ws, size_t ws_size,
                              hipStream_t stream) {
    const float* x   = (const float*)d_in[0];
    const int*   ei  = (const int*)d_in[1];      // [2, N_EDGES] int32
    const float* W1  = (const float*)d_in[2];
    const float* b1  = (const float*)d_in[3];
    const float* lw1 = (const float*)d_in[4];
    const float* lb1 = (const float*)d_in[5];
    const float* lw2 = (const float*)d_in[6];
    const float* lb2 = (const float*)d_in[7];
    const float* lw3 = (const float*)d_in[8];
    const float* lb3 = (const float*)d_in[9];
    float* out = (float*)d_out;

    const int* src = ei;
    const int* dst = ei + N_EDGES;

    // workspace carve-up (256B aligned)
    char* ws = (char*)d_ws;
    size_t off = 0;
    auto alloc = [&](size_t bytes) {
        char* p = ws + off;
        off = (off + bytes + 255) & ~(size_t)255;
        return p;
    };
    float* hs   = (float*)alloc((size_t)N_NODES * H1 * sizeof(float));
    float* agg  = (float*)alloc((size_t)N_NODES * H1 * sizeof(float));
    float* deg  = (float*)alloc((size_t)N_NODES * sizeof(float));
    float* dinv = (float*)alloc((size_t)N_NODES * sizeof(float));
    float* g    = (float*)alloc((size_t)H1 * sizeof(float));
    (void)ws_size;

    hipMemsetAsync(agg, 0, (size_t)N_NODES * H1 * sizeof(float), stream);
    hipMemsetAsync(g, 0, (size_t)H1 * sizeof(float), stream);

    init_deg_kernel<<<(N_NODES + 255) / 256, 256, 0, stream>>>(deg);
    count_deg_kernel<<<1024, 256, 0, stream>>>(dst, deg);
    dinv_kernel<<<(N_NODES + 255) / 256, 256, 0, stream>>>(deg, dinv);

    gemm_kernel<<<(N_NODES + GEMM_NODES - 1) / GEMM_NODES, 256, 0, stream>>>(x, W1, dinv, hs);

    aggregate_kernel<<<2048, 256, 0, stream>>>(src, dst, hs, agg);

    pool_kernel<<<512, 128, 0, stream>>>(agg, hs, dinv, b1, g);

    mlp_kernel<<<1, 128, 0, stream>>>(g, lw1, lb1, lw2, lb2, lw3, lb3, out);
}

// Round 2
// 383.722 us; speedup vs baseline: 1.0735x; 1.0735x over previous
//
#include <hip/hip_runtime.h>

#define N_NODES 50000
#define N_EDGES 800000
#define D_IN 128
#define H1 96
#define H2 64
#define GEMM_NODES 32
#define SCAN_T 1024
#define SCAN_C 49   // ceil(50000/1024)

// ---------------- degree histogram (deg counts in-edges; +1 self-loop added in scan) ----------
__global__ void count_deg_kernel(const int* __restrict__ dst, float* __restrict__ deg) {
    int i = blockIdx.x * blockDim.x + threadIdx.x;
    int stride = gridDim.x * blockDim.x;
    for (int e = i; e < N_EDGES; e += stride)
        atomicAdd(&deg[dst[e]], 1.0f);
}

// ---------------- single-block exclusive scan -> row_start/cursor, plus dinv ----------------
__global__ __launch_bounds__(SCAN_T) void scan_kernel(const float* __restrict__ deg,
                                                      int* __restrict__ row_start,
                                                      int* __restrict__ cursor,
                                                      float* __restrict__ dinv) {
    __shared__ int s[SCAN_T];
    int t = threadIdx.x;
    int begin = t * SCAN_C;
    int end = begin + SCAN_C;
    if (end > N_NODES) end = N_NODES;
    if (begin > N_NODES) begin = N_NODES;

    int sum = 0;
    for (int i = begin; i < end; ++i) sum += (int)deg[i];
    s[t] = sum;
    __syncthreads();
    // Hillis-Steele inclusive scan
    for (int off = 1; off < SCAN_T; off <<= 1) {
        int v = (t >= off) ? s[t - off] : 0;
        __syncthreads();
        s[t] += v;
        __syncthreads();
    }
    int run = s[t] - sum;  // exclusive prefix
    for (int i = begin; i < end; ++i) {
        int c = (int)deg[i];
        row_start[i] = run;
        cursor[i] = run;
        dinv[i] = rsqrtf((float)c + 1.0f);  // +1 self-loop
        run += c;
    }
    if (t == SCAN_T - 1) row_start[N_NODES] = run;  // == N_EDGES
}

// ---------------- scatter edges into CSR (index-only atomics) ----------------
__global__ void scatter_kernel(const int* __restrict__ src, const int* __restrict__ dst,
                               int* __restrict__ cursor, int* __restrict__ sorted_src) {
    int i = blockIdx.x * blockDim.x + threadIdx.x;
    int stride = gridDim.x * blockDim.x;
    for (int e = i; e < N_EDGES; e += stride) {
        int d = dst[e];
        int pos = atomicAdd(&cursor[d], 1);
        sorted_src[pos] = src[e];
    }
}

// ---------------- hs = (x @ W1) * dinv[n] ----------------
__global__ __launch_bounds__(256) void gemm_kernel(const float* __restrict__ x,
                                                   const float* __restrict__ W1,
                                                   const float* __restrict__ dinv,
                                                   float* __restrict__ hs) {
    __shared__ float sW[D_IN * H1];          // 48 KB
    __shared__ float sx[GEMM_NODES * D_IN];  // 16 KB
    int tid = threadIdx.x;

    for (int i = tid; i < D_IN * H1 / 4; i += 256)
        ((float4*)sW)[i] = ((const float4*)W1)[i];

    int base = blockIdx.x * GEMM_NODES;
    const float4* x4 = (const float4*)x;
    for (int i = tid; i < GEMM_NODES * D_IN / 4; i += 256) {
        int n = base + i / (D_IN / 4);
        if (n < N_NODES) ((float4*)sx)[i] = x4[(size_t)base * (D_IN / 4) + i];
    }
    __syncthreads();

    int fg = tid & 31;
    int ng = tid >> 5;

    float acc[4][3];
#pragma unroll
    for (int i = 0; i < 4; ++i)
#pragma unroll
        for (int j = 0; j < 3; ++j) acc[i][j] = 0.0f;

#pragma unroll 4
    for (int k = 0; k < D_IN; ++k) {
        float w0 = sW[k * H1 + fg];
        float w1 = sW[k * H1 + fg + 32];
        float w2 = sW[k * H1 + fg + 64];
#pragma unroll
        for (int i = 0; i < 4; ++i) {
            float xv = sx[(ng * 4 + i) * D_IN + k];
            acc[i][0] = fmaf(xv, w0, acc[i][0]);
            acc[i][1] = fmaf(xv, w1, acc[i][1]);
            acc[i][2] = fmaf(xv, w2, acc[i][2]);
        }
    }

#pragma unroll
    for (int i = 0; i < 4; ++i) {
        int n = base + ng * 4 + i;
        if (n < N_NODES) {
            float dv = dinv[n];
            hs[(size_t)n * H1 + fg]      = acc[i][0] * dv;
            hs[(size_t)n * H1 + fg + 32] = acc[i][1] * dv;
            hs[(size_t)n * H1 + fg + 64] = acc[i][2] * dv;
        }
    }
}

// ---------------- fused pull-aggregate + ReLU + sum-pool ----------------
// 128-thread group per node (f = tid&127, active f<96); grid-stride over nodes;
// pooled partial kept in a register per lane, one atomicAdd per feature per block.
__global__ __launch_bounds__(256) void agg_pool_kernel(const float* __restrict__ hs,
                                                       const int* __restrict__ row_start,
                                                       const int* __restrict__ sorted_src,
                                                       const float* __restrict__ dinv,
                                                       const float* __restrict__ b1,
                                                       float* __restrict__ g) {
    int tid = threadIdx.x;
    int grp = tid >> 7;
    int f = tid & 127;
    bool act = f < H1;
    float bf = act ? b1[f] : 0.0f;
    float gacc = 0.0f;

    for (int n = blockIdx.x * 2 + grp; n < N_NODES; n += gridDim.x * 2) {
        float acc = act ? hs[(size_t)n * H1 + f] : 0.0f;  // self-loop term
        int e = row_start[n];
        int eend = row_start[n + 1];
        // unroll by 4 for memory-level parallelism
        for (; e + 4 <= eend; e += 4) {
            int s0 = sorted_src[e];
            int s1 = sorted_src[e + 1];
            int s2 = sorted_src[e + 2];
            int s3 = sorted_src[e + 3];
            if (act) {
                float v0 = hs[(size_t)s0 * H1 + f];
                float v1 = hs[(size_t)s1 * H1 + f];
                float v2 = hs[(size_t)s2 * H1 + f];
                float v3 = hs[(size_t)s3 * H1 + f];
                acc += (v0 + v1) + (v2 + v3);
            }
        }
        for (; e < eend; ++e) {
            int s = sorted_src[e];
            if (act) acc += hs[(size_t)s * H1 + f];
        }
        if (act) gacc += fmaxf(fmaf(dinv[n], acc, bf), 0.0f);
    }

    // combine the two groups in LDS, then one atomic per feature per block
    __shared__ float sg[H1];
    if (grp == 0 && act) sg[f] = gacc;
    __syncthreads();
    if (grp == 1 && act) atomicAdd(&sg[f], gacc);
    __syncthreads();
    if (grp == 0 && act) atomicAdd(&g[f], sg[f]);
}

// ---------------- tiny MLP head ----------------
__global__ void mlp_kernel(const float* __restrict__ g,
                           const float* __restrict__ lw1, const float* __restrict__ lb1,
                           const float* __restrict__ lw2, const float* __restrict__ lb2,
                           const float* __restrict__ lw3, const float* __restrict__ lb3,
                           float* __restrict__ out) {
    __shared__ float sg[H1], v1[H1], v2[H2];
    int t = threadIdx.x;  // blockDim = 128
    if (t < H1) sg[t] = g[t];
    __syncthreads();
    if (t < H1) {
        float a = lb1[t];
        for (int k = 0; k < H1; ++k) a = fmaf(sg[k], lw1[k * H1 + t], a);
        v1[t] = fmaxf(a, 0.0f);
    }
    __syncthreads();
    if (t < H2) {
        float a = lb2[t];
        for (int k = 0; k < H1; ++k) a = fmaf(v1[k], lw2[k * H2 + t], a);
        v2[t] = fmaxf(a, 0.0f);
    }
    __syncthreads();
    if (t == 0) {
        float a = lb3[0];
        for (int k = 0; k < H2; ++k) a = fmaf(v2[k], lw3[k], a);
        out[0] = a;
    }
}

extern "C" void kernel_launch(void* const* d_in, const int* in_sizes, int n_in,
                              void* d_out, int out_size, void* d_ws, size_t ws_size,
                              hipStream_t stream) {
    const float* x   = (const float*)d_in[0];
    const int*   ei  = (const int*)d_in[1];      // [2, N_EDGES] int32
    const float* W1  = (const float*)d_in[2];
    const float* b1  = (const float*)d_in[3];
    const float* lw1 = (const float*)d_in[4];
    const float* lb1 = (const float*)d_in[5];
    const float* lw2 = (const float*)d_in[6];
    const float* lb2 = (const float*)d_in[7];
    const float* lw3 = (const float*)d_in[8];
    const float* lb3 = (const float*)d_in[9];
    float* out = (float*)d_out;

    const int* src = ei;
    const int* dst = ei + N_EDGES;

    char* ws = (char*)d_ws;
    size_t off = 0;
    auto alloc = [&](size_t bytes) {
        char* p = ws + off;
        off = (off + bytes + 255) & ~(size_t)255;
        return p;
    };
    // deg and g adjacent so one memset clears both
    float* deg        = (float*)alloc((size_t)N_NODES * sizeof(float));
    float* g          = (float*)alloc((size_t)H1 * sizeof(float));
    float* dinv       = (float*)alloc((size_t)N_NODES * sizeof(float));
    int*   row_start  = (int*)alloc((size_t)(N_NODES + 1) * sizeof(int));
    int*   cursor     = (int*)alloc((size_t)N_NODES * sizeof(int));
    int*   sorted_src = (int*)alloc((size_t)N_EDGES * sizeof(int));
    float* hs         = (float*)alloc((size_t)N_NODES * H1 * sizeof(float));
    (void)ws_size;

    // clear deg + g in one shot (they're contiguous in ws)
    hipMemsetAsync(deg, 0, (char*)(g + H1) - (char*)deg, stream);

    count_deg_kernel<<<2048, 256, 0, stream>>>(dst, deg);
    scan_kernel<<<1, SCAN_T, 0, stream>>>(deg, row_start, cursor, dinv);
    scatter_kernel<<<2048, 256, 0, stream>>>(src, dst, cursor, sorted_src);

    gemm_kernel<<<(N_NODES + GEMM_NODES - 1) / GEMM_NODES, 256, 0, stream>>>(x, W1, dinv, hs);

    agg_pool_kernel<<<2048, 256, 0, stream>>>(hs, row_start, sorted_src, dinv, b1, g);

    mlp_kernel<<<1, 128, 0, stream>>>(g, lw1, lb1, lw2, lb2, lw3, lb3, out);
}

// Round 3
// 258.655 us; speedup vs baseline: 1.5926x; 1.4835x over previous
//
#include <hip/hip_runtime.h>

#define N_NODES 50000
#define N_EDGES 800000
#define D_IN 128
#define H1 96
#define H2 64
#define GEMM_NODES 32
#define SCAN_BLK 256
#define N_SBLK ((N_NODES + SCAN_BLK - 1) / SCAN_BLK)   // 196

// ---------------- degree histogram (int in-degree; +1 self-loop applied later) ----------
__global__ void count_deg_kernel(const int* __restrict__ dst, int* __restrict__ deg) {
    int i = blockIdx.x * blockDim.x + threadIdx.x;
    int stride = gridDim.x * blockDim.x;
    for (int e = i; e < N_EDGES; e += stride)
        atomicAdd(&deg[dst[e]], 1);
}

// ---------------- 3-phase device-wide exclusive scan ----------------
// Phase A: per-block (256-elem) sums
__global__ __launch_bounds__(SCAN_BLK) void deg_part_kernel(const int* __restrict__ deg,
                                                            int* __restrict__ block_sums) {
    __shared__ int s[SCAN_BLK];
    int t = threadIdx.x;
    int i = blockIdx.x * SCAN_BLK + t;
    s[t] = (i < N_NODES) ? deg[i] : 0;
    __syncthreads();
    for (int off = SCAN_BLK / 2; off > 0; off >>= 1) {
        if (t < off) s[t] += s[t + off];
        __syncthreads();
    }
    if (t == 0) block_sums[blockIdx.x] = s[0];
}

// Phase B: single-block exclusive scan of the 196 block sums
__global__ __launch_bounds__(SCAN_BLK) void block_scan_kernel(int* __restrict__ block_sums) {
    __shared__ int s[SCAN_BLK];
    int t = threadIdx.x;
    int v = (t < N_SBLK) ? block_sums[t] : 0;
    s[t] = v;
    __syncthreads();
    for (int off = 1; off < SCAN_BLK; off <<= 1) {
        int u = (t >= off) ? s[t - off] : 0;
        __syncthreads();
        s[t] += u;
        __syncthreads();
    }
    if (t < N_SBLK) block_sums[t] = s[t] - v;  // exclusive
}

// Phase C: in-block scan + block offset -> row_start/cursor/dinv
__global__ __launch_bounds__(SCAN_BLK) void deg_scan_kernel(const int* __restrict__ deg,
                                                            const int* __restrict__ block_off,
                                                            int* __restrict__ row_start,
                                                            int* __restrict__ cursor,
                                                            float* __restrict__ dinv) {
    __shared__ int s[SCAN_BLK];
    int t = threadIdx.x;
    int i = blockIdx.x * SCAN_BLK + t;
    int v = (i < N_NODES) ? deg[i] : 0;
    s[t] = v;
    __syncthreads();
    for (int off = 1; off < SCAN_BLK; off <<= 1) {
        int u = (t >= off) ? s[t - off] : 0;
        __syncthreads();
        s[t] += u;
        __syncthreads();
    }
    int excl = s[t] - v + block_off[blockIdx.x];
    if (i < N_NODES) {
        row_start[i] = excl;
        cursor[i] = excl;
        dinv[i] = rsqrtf((float)v + 1.0f);  // +1 self-loop
    }
    if (i == 0) row_start[N_NODES] = N_EDGES;  // total in-degree == edge count
}

// ---------------- scatter edges into CSR (index-only atomics) ----------------
__global__ void scatter_kernel(const int* __restrict__ src, const int* __restrict__ dst,
                               int* __restrict__ cursor, int* __restrict__ sorted_src) {
    int i = blockIdx.x * blockDim.x + threadIdx.x;
    int stride = gridDim.x * blockDim.x;
    for (int e = i; e < N_EDGES; e += stride) {
        int d = dst[e];
        int pos = atomicAdd(&cursor[d], 1);
        sorted_src[pos] = src[e];
    }
}

// ---------------- hs = (x @ W1) * dinv[n] ----------------
__global__ __launch_bounds__(256) void gemm_kernel(const float* __restrict__ x,
                                                   const float* __restrict__ W1,
                                                   const float* __restrict__ dinv,
                                                   float* __restrict__ hs) {
    __shared__ float sW[D_IN * H1];          // 48 KB
    __shared__ float sx[GEMM_NODES * D_IN];  // 16 KB
    int tid = threadIdx.x;

    for (int i = tid; i < D_IN * H1 / 4; i += 256)
        ((float4*)sW)[i] = ((const float4*)W1)[i];

    int base = blockIdx.x * GEMM_NODES;
    const float4* x4 = (const float4*)x;
    for (int i = tid; i < GEMM_NODES * D_IN / 4; i += 256) {
        int n = base + i / (D_IN / 4);
        if (n < N_NODES) ((float4*)sx)[i] = x4[(size_t)base * (D_IN / 4) + i];
    }
    __syncthreads();

    int fg = tid & 31;
    int ng = tid >> 5;

    float acc[4][3];
#pragma unroll
    for (int i = 0; i < 4; ++i)
#pragma unroll
        for (int j = 0; j < 3; ++j) acc[i][j] = 0.0f;

#pragma unroll 4
    for (int k = 0; k < D_IN; ++k) {
        float w0 = sW[k * H1 + fg];
        float w1 = sW[k * H1 + fg + 32];
        float w2 = sW[k * H1 + fg + 64];
#pragma unroll
        for (int i = 0; i < 4; ++i) {
            float xv = sx[(ng * 4 + i) * D_IN + k];
            acc[i][0] = fmaf(xv, w0, acc[i][0]);
            acc[i][1] = fmaf(xv, w1, acc[i][1]);
            acc[i][2] = fmaf(xv, w2, acc[i][2]);
        }
    }

#pragma unroll
    for (int i = 0; i < 4; ++i) {
        int n = base + ng * 4 + i;
        if (n < N_NODES) {
            float dv = dinv[n];
            hs[(size_t)n * H1 + fg]      = acc[i][0] * dv;
            hs[(size_t)n * H1 + fg + 32] = acc[i][1] * dv;
            hs[(size_t)n * H1 + fg + 64] = acc[i][2] * dv;
        }
    }
}

// ---------------- fused pull-aggregate + ReLU + sum-pool ----------------
__global__ __launch_bounds__(256) void agg_pool_kernel(const float* __restrict__ hs,
                                                       const int* __restrict__ row_start,
                                                       const int* __restrict__ sorted_src,
                                                       const float* __restrict__ dinv,
                                                       const float* __restrict__ b1,
                                                       float* __restrict__ g) {
    int tid = threadIdx.x;
    int grp = tid >> 7;
    int f = tid & 127;
    bool act = f < H1;
    float bf = act ? b1[f] : 0.0f;
    float gacc = 0.0f;

    for (int n = blockIdx.x * 2 + grp; n < N_NODES; n += gridDim.x * 2) {
        float acc = act ? hs[(size_t)n * H1 + f] : 0.0f;  // self-loop term
        int e = row_start[n];
        int eend = row_start[n + 1];
        for (; e + 4 <= eend; e += 4) {
            int s0 = sorted_src[e];
            int s1 = sorted_src[e + 1];
            int s2 = sorted_src[e + 2];
            int s3 = sorted_src[e + 3];
            if (act) {
                float v0 = hs[(size_t)s0 * H1 + f];
                float v1 = hs[(size_t)s1 * H1 + f];
                float v2 = hs[(size_t)s2 * H1 + f];
                float v3 = hs[(size_t)s3 * H1 + f];
                acc += (v0 + v1) + (v2 + v3);
            }
        }
        for (; e < eend; ++e) {
            int s = sorted_src[e];
            if (act) acc += hs[(size_t)s * H1 + f];
        }
        if (act) gacc += fmaxf(fmaf(dinv[n], acc, bf), 0.0f);
    }

    __shared__ float sg[H1];
    if (grp == 0 && act) sg[f] = gacc;
    __syncthreads();
    if (grp == 1 && act) atomicAdd(&sg[f], gacc);
    __syncthreads();
    if (grp == 0 && act) atomicAdd(&g[f], sg[f]);
}

// ---------------- tiny MLP head ----------------
__global__ void mlp_kernel(const float* __restrict__ g,
                           const float* __restrict__ lw1, const float* __restrict__ lb1,
                           const float* __restrict__ lw2, const float* __restrict__ lb2,
                           const float* __restrict__ lw3, const float* __restrict__ lb3,
                           float* __restrict__ out) {
    __shared__ float sg[H1], v1[H1], v2[H2];
    int t = threadIdx.x;  // blockDim = 128
    if (t < H1) sg[t] = g[t];
    __syncthreads();
    if (t < H1) {
        float a = lb1[t];
        for (int k = 0; k < H1; ++k) a = fmaf(sg[k], lw1[k * H1 + t], a);
        v1[t] = fmaxf(a, 0.0f);
    }
    __syncthreads();
    if (t < H2) {
        float a = lb2[t];
        for (int k = 0; k < H1; ++k) a = fmaf(v1[k], lw2[k * H2 + t], a);
        v2[t] = fmaxf(a, 0.0f);
    }
    __syncthreads();
    if (t == 0) {
        float a = lb3[0];
        for (int k = 0; k < H2; ++k) a = fmaf(v2[k], lw3[k], a);
        out[0] = a;
    }
}

extern "C" void kernel_launch(void* const* d_in, const int* in_sizes, int n_in,
                              void* d_out, int out_size, void* d_ws, size_t ws_size,
                              hipStream_t stream) {
    const float* x   = (const float*)d_in[0];
    const int*   ei  = (const int*)d_in[1];      // [2, N_EDGES] int32
    const float* W1  = (const float*)d_in[2];
    const float* b1  = (const float*)d_in[3];
    const float* lw1 = (const float*)d_in[4];
    const float* lb1 = (const float*)d_in[5];
    const float* lw2 = (const float*)d_in[6];
    const float* lb2 = (const float*)d_in[7];
    const float* lw3 = (const float*)d_in[8];
    const float* lb3 = (const float*)d_in[9];
    float* out = (float*)d_out;

    const int* src = ei;
    const int* dst = ei + N_EDGES;

    char* ws = (char*)d_ws;
    size_t off = 0;
    auto alloc = [&](size_t bytes) {
        char* p = ws + off;
        off = (off + bytes + 255) & ~(size_t)255;
        return p;
    };
    // deg and g adjacent so one memset clears both
    int*   deg        = (int*)alloc((size_t)N_NODES * sizeof(int));
    float* g          = (float*)alloc((size_t)H1 * sizeof(float));
    float* dinv       = (float*)alloc((size_t)N_NODES * sizeof(float));
    int*   row_start  = (int*)alloc((size_t)(N_NODES + 1) * sizeof(int));
    int*   cursor     = (int*)alloc((size_t)N_NODES * sizeof(int));
    int*   block_sums = (int*)alloc((size_t)N_SBLK * sizeof(int));
    int*   sorted_src = (int*)alloc((size_t)N_EDGES * sizeof(int));
    float* hs         = (float*)alloc((size_t)N_NODES * H1 * sizeof(float));
    (void)ws_size;

    hipMemsetAsync(deg, 0, (char*)(g + H1) - (char*)deg, stream);

    count_deg_kernel<<<2048, 256, 0, stream>>>(dst, deg);
    deg_part_kernel<<<N_SBLK, SCAN_BLK, 0, stream>>>(deg, block_sums);
    block_scan_kernel<<<1, SCAN_BLK, 0, stream>>>(block_sums);
    deg_scan_kernel<<<N_SBLK, SCAN_BLK, 0, stream>>>(deg, block_sums, row_start, cursor, dinv);
    scatter_kernel<<<2048, 256, 0, stream>>>(src, dst, cursor, sorted_src);

    gemm_kernel<<<(N_NODES + GEMM_NODES - 1) / GEMM_NODES, 256, 0, stream>>>(x, W1, dinv, hs);

    agg_pool_kernel<<<2048, 256, 0, stream>>>(hs, row_start, sorted_src, dinv, b1, g);

    mlp_kernel<<<1, 128, 0, stream>>>(g, lw1, lb1, lw2, lb2, lw3, lb3, out);
}